// Round 1
// baseline (2416.046 us; speedup 1.0000x reference)
//
#include <hip/hip_runtime.h>
#include <stdint.h>

// M-RNN bidirectional GRU imputation kernel for MI355X (gfx950).
// B=512, T=128, V=59, H=512. All inputs fp32; compute in bf16 MFMA + fp32 state.

typedef unsigned short ushort_t;
typedef __bf16 bf16x8 __attribute__((ext_vector_type(8)));
typedef float f32x4 __attribute__((ext_vector_type(4)));

__device__ __forceinline__ ushort_t f2bf(float f) {
    union { float f; uint32_t u; } c; c.f = f;
    uint32_t u = c.u;
    uint32_t r = (u + 0x7FFFu + ((u >> 16) & 1u)) >> 16;
    return (ushort_t)r;
}

// ---------------------------------------------------------------------------
// prep: zero state, bf16-convert weights, build xcat panels [t][b][192]
// xcat_f[t][b] = [values[b,t,:], masks[b,t,:], deltas_f[b,t,:], 0*15]
// xcat_b[t][b] = [values[b,127-t,:], masks[b,127-t,:], deltas_b[b,t,:], 0*15]
// ---------------------------------------------------------------------------
__global__ void prep_kernel(const float* __restrict__ values, const float* __restrict__ masks,
                            const float* __restrict__ deltas_f, const float* __restrict__ deltas_b,
                            const float* __restrict__ Wih, const float* __restrict__ Whh,
                            const float* __restrict__ Wh,
                            ushort_t* __restrict__ xcat_f, ushort_t* __restrict__ xcat_b,
                            ushort_t* __restrict__ WhhB, ushort_t* __restrict__ WihB,
                            ushort_t* __restrict__ WhpB,
                            ushort_t* __restrict__ hf0, ushort_t* __restrict__ hb0,
                            float* __restrict__ hstate)
{
    long long gid = (long long)blockIdx.x * blockDim.x + threadIdx.x;
    long long stride = (long long)gridDim.x * blockDim.x;

    for (long long i = gid; i < 1024LL * 512; i += stride) hstate[i] = 0.f;
    for (long long i = gid; i < 512LL * 512; i += stride) { hf0[i] = 0; hb0[i] = 0; }
    for (long long i = gid; i < 1536LL * 512; i += stride) WhhB[i] = f2bf(Whh[i]);
    for (long long i = gid; i < 1536LL * 192; i += stride) {
        int n = (int)(i / 192), c = (int)(i % 192);
        WihB[i] = (c < 177) ? f2bf(Wih[n * 177 + c]) : (ushort_t)0;
    }
    for (long long i = gid; i < 64LL * 1024; i += stride) {
        int n = (int)(i >> 10), k = (int)(i & 1023);
        WhpB[i] = (n < 59) ? f2bf(Wh[n * 1024 + k]) : (ushort_t)0;
    }
    for (long long i = gid; i < 128LL * 512 * 192; i += stride) {
        int c = (int)(i % 192);
        long long tb = i / 192;
        int b = (int)(tb % 512);
        int t = (int)(tb / 512);
        float vf = 0.f;
        if (c < 59)       vf = values  [((long long)b * 128 + t) * 59 + c];
        else if (c < 118) vf = masks   [((long long)b * 128 + t) * 59 + (c - 59)];
        else if (c < 177) vf = deltas_f[((long long)b * 128 + t) * 59 + (c - 118)];
        xcat_f[i] = (c < 177) ? f2bf(vf) : (ushort_t)0;
        int tr = 127 - t;
        float vb = 0.f;
        if (c < 59)       vb = values  [((long long)b * 128 + tr) * 59 + c];
        else if (c < 118) vb = masks   [((long long)b * 128 + tr) * 59 + (c - 59)];
        else if (c < 177) vb = deltas_b[((long long)b * 128 + t)  * 59 + (c - 118)];
        xcat_b[i] = (c < 177) ? f2bf(vb) : (ushort_t)0;
    }
}

// ---------------------------------------------------------------------------
// step: one GRU step for both directions (M=1024 rows).
// Block tile: 64 rows x 32 units (x3 gates). Grid (16 ublk, 16 mblk), 512 thr.
// K-loop: 8 chunks of h (K=512) + 3 chunks of xcat (K=192).
// r/z accumulate h-part and x-part together; n keeps them separate.
// Epilogue: GRU cell, fp32 state update in place, bf16 h into history slot t+1.
// ---------------------------------------------------------------------------
__global__ __launch_bounds__(512)
void step_kernel(const ushort_t* __restrict__ hsrcF, const ushort_t* __restrict__ hsrcB,
                 ushort_t* __restrict__ hdstF, ushort_t* __restrict__ hdstB,
                 const ushort_t* __restrict__ xF, const ushort_t* __restrict__ xB,
                 const ushort_t* __restrict__ WhhB, const ushort_t* __restrict__ WihB,
                 const float* __restrict__ bih, const float* __restrict__ bhh,
                 float* __restrict__ hstate)
{
    __shared__ __align__(16) ushort_t As[64 * 64];
    __shared__ __align__(16) ushort_t Bs[96 * 64];

    const int tid  = threadIdx.x;
    const int ublk = blockIdx.x;            // 0..15 -> 32 units each
    const int mblk = blockIdx.y;            // 0..15 -> 64 rows each
    const int u0   = ublk * 32;
    const bool fwd = (mblk < 8);
    const ushort_t* hsrc = fwd ? hsrcF : hsrcB;
    const ushort_t* xsrc = fwd ? xF : xB;
    ushort_t* hdst = fwd ? hdstF : hdstB;
    const int rbase = (fwd ? mblk : mblk - 8) * 64;  // row base within direction

    const int lane = tid & 63;
    const int wv   = tid >> 6;              // 0..7
    const int mt   = wv >> 1;               // m-tile 0..3 (16 rows each)
    const int tc   = wv & 1;                // unit sub-tile 0..1 (16 units each)
    const int l15  = lane & 15;
    const int lhi  = lane >> 4;

    f32x4 zero = {0.f, 0.f, 0.f, 0.f};
    f32x4 accR = zero, accZ = zero, accNH = zero, accNX = zero;

    const int arow = tid >> 3;              // 0..63
    const int ac8  = (tid & 7) * 8;         // element offset within row

    for (int chunk = 0; chunk < 11; ++chunk) {
        const bool ph1 = (chunk < 8);
        // stage A (64x64)
        {
            const ushort_t* src = ph1
                ? hsrc + ((size_t)(rbase + arow)) * 512 + chunk * 64 + ac8
                : xsrc + ((size_t)(rbase + arow)) * 192 + (chunk - 8) * 64 + ac8;
            *(uint4*)&As[arow * 64 + ac8] = *(const uint4*)src;
        }
        // stage B (96x64): rows 0..31 r-gate, 32..63 z-gate, 64..95 n-gate
        {
            int rowB = tid >> 3; int c8 = (tid & 7) * 8;
            int g = rowB >> 5; int u = u0 + (rowB & 31);
            const ushort_t* src = ph1
                ? WhhB + ((size_t)(g * 512 + u)) * 512 + chunk * 64 + c8
                : WihB + ((size_t)(g * 512 + u)) * 192 + (chunk - 8) * 64 + c8;
            *(uint4*)&Bs[rowB * 64 + c8] = *(const uint4*)src;
            if (tid < 256) {
                int u2 = tid + 512;
                rowB = u2 >> 3; c8 = (u2 & 7) * 8;
                g = rowB >> 5; u = u0 + (rowB & 31);
                src = ph1
                    ? WhhB + ((size_t)(g * 512 + u)) * 512 + chunk * 64 + c8
                    : WihB + ((size_t)(g * 512 + u)) * 192 + (chunk - 8) * 64 + c8;
                *(uint4*)&Bs[rowB * 64 + c8] = *(const uint4*)src;
            }
        }
        __syncthreads();
        #pragma unroll
        for (int ks = 0; ks < 64; ks += 32) {
            bf16x8 a  = *(const bf16x8*)&As[(mt * 16 + l15) * 64 + ks + lhi * 8];
            bf16x8 b0 = *(const bf16x8*)&Bs[( 0 + tc * 16 + l15) * 64 + ks + lhi * 8];
            bf16x8 b1 = *(const bf16x8*)&Bs[(32 + tc * 16 + l15) * 64 + ks + lhi * 8];
            bf16x8 b2 = *(const bf16x8*)&Bs[(64 + tc * 16 + l15) * 64 + ks + lhi * 8];
            accR = __builtin_amdgcn_mfma_f32_16x16x32_bf16(a, b0, accR, 0, 0, 0);
            accZ = __builtin_amdgcn_mfma_f32_16x16x32_bf16(a, b1, accZ, 0, 0, 0);
            if (ph1) accNH = __builtin_amdgcn_mfma_f32_16x16x32_bf16(a, b2, accNH, 0, 0, 0);
            else     accNX = __builtin_amdgcn_mfma_f32_16x16x32_bf16(a, b2, accNX, 0, 0, 0);
        }
        __syncthreads();
    }

    // epilogue: GRU cell
    const int u = u0 + tc * 16 + l15;
    const float bR  = bih[u] + bhh[u];
    const float bZ  = bih[512 + u] + bhh[512 + u];
    const float bNX = bih[1024 + u];
    const float bNH = bhh[1024 + u];
    #pragma unroll
    for (int reg = 0; reg < 4; ++reg) {
        int m = mblk * 64 + mt * 16 + lhi * 4 + reg;   // global row 0..1023
        float r = 1.f / (1.f + __expf(-(accR[reg] + bR)));
        float z = 1.f / (1.f + __expf(-(accZ[reg] + bZ)));
        float n = tanhf(accNX[reg] + bNX + r * (accNH[reg] + bNH));
        size_t idx = (size_t)m * 512 + u;
        float hold = hstate[idx];
        float hnew = (1.f - z) * n + z * hold;
        hstate[idx] = hnew;
        size_t bloc = (size_t)(fwd ? m : m - 512) * 512 + u;
        hdst[bloc] = f2bf(hnew);
    }
}

// ---------------------------------------------------------------------------
// x_v = [hf, hb_rev] @ Wh^T + bh.  Block = one batch b (128 rows = all t).
// K = 1024 (512 fwd + 512 bwd), N = 64 (59 valid). 256 threads, 4 waves.
// ---------------------------------------------------------------------------
__global__ __launch_bounds__(256)
void xv_kernel(const ushort_t* __restrict__ hf, const ushort_t* __restrict__ hb,
               const ushort_t* __restrict__ WhpB, const float* __restrict__ bh,
               float* __restrict__ x_v)
{
    __shared__ __align__(16) ushort_t As[128 * 64];
    __shared__ __align__(16) ushort_t Bs[64 * 64];
    const int b = blockIdx.x;
    const int tid = threadIdx.x;
    const int lane = tid & 63, wv = tid >> 6;
    const int l15 = lane & 15, lhi = lane >> 4;

    f32x4 zero = {0.f, 0.f, 0.f, 0.f};
    f32x4 acc[2][4];
    #pragma unroll
    for (int i = 0; i < 2; ++i)
        #pragma unroll
        for (int j = 0; j < 4; ++j) acc[i][j] = zero;

    for (int chunk = 0; chunk < 16; ++chunk) {
        const bool fw = (chunk < 8);
        #pragma unroll
        for (int s = 0; s < 4; ++s) {
            int unit = tid + s * 256;
            int row = unit >> 3;           // = t
            int c8 = (unit & 7) * 8;
            const ushort_t* src = fw
                ? hf + ((size_t)row * 512 + b) * 512 + chunk * 64 + c8
                : hb + ((size_t)(127 - row) * 512 + b) * 512 + (chunk - 8) * 64 + c8;
            *(uint4*)&As[row * 64 + c8] = *(const uint4*)src;
        }
        #pragma unroll
        for (int s = 0; s < 2; ++s) {
            int unit = tid + s * 256;
            int row = unit >> 3;
            int c8 = (unit & 7) * 8;
            *(uint4*)&Bs[row * 64 + c8] =
                *(const uint4*)(WhpB + (size_t)row * 1024 + chunk * 64 + c8);
        }
        __syncthreads();
        #pragma unroll
        for (int ks = 0; ks < 64; ks += 32) {
            bf16x8 bfr[4];
            #pragma unroll
            for (int nt = 0; nt < 4; ++nt)
                bfr[nt] = *(const bf16x8*)&Bs[(nt * 16 + l15) * 64 + ks + lhi * 8];
            #pragma unroll
            for (int mt2 = 0; mt2 < 2; ++mt2) {
                bf16x8 a = *(const bf16x8*)&As[(wv * 32 + mt2 * 16 + l15) * 64 + ks + lhi * 8];
                #pragma unroll
                for (int nt = 0; nt < 4; ++nt)
                    acc[mt2][nt] = __builtin_amdgcn_mfma_f32_16x16x32_bf16(a, bfr[nt], acc[mt2][nt], 0, 0, 0);
            }
        }
        __syncthreads();
    }
    #pragma unroll
    for (int mt2 = 0; mt2 < 2; ++mt2) {
        #pragma unroll
        for (int nt = 0; nt < 4; ++nt) {
            int col = nt * 16 + l15;
            if (col < 59) {
                float bhc = bh[col];
                #pragma unroll
                for (int reg = 0; reg < 4; ++reg) {
                    int t = wv * 32 + mt2 * 16 + lhi * 4 + reg;
                    x_v[((size_t)b * 128 + t) * 59 + col] = acc[mt2][nt][reg] + bhc;
                }
            }
        }
    }
}

// ---------------------------------------------------------------------------
// post: feat_reg (zero diag) + weight_combine + imputation + x_imp + loss partials.
// Block = one batch b; wave handles one (b,t) row; lane j = feature.
// ---------------------------------------------------------------------------
__global__ __launch_bounds__(256)
void post_kernel(const float* __restrict__ values, const float* __restrict__ masks,
                 const float* __restrict__ x_v,
                 const float* __restrict__ Wf, const float* __restrict__ bf_,
                 const float* __restrict__ Wc, const float* __restrict__ bc,
                 const float* __restrict__ Wi, const float* __restrict__ bi,
                 float* __restrict__ out, float* __restrict__ pnum, float* __restrict__ pden)
{
    __shared__ float WfL[59 * 59];
    __shared__ float WcL[59 * 118];
    __shared__ float WiL[59 * 59];
    __shared__ float bcombL[64], biL[64];
    const int tid = threadIdx.x;
    for (int i = tid; i < 59 * 59; i += 256) { int r = i / 59, c = i % 59; WfL[i] = (r == c) ? 0.f : Wf[i]; }
    for (int i = tid; i < 59 * 118; i += 256) WcL[i] = Wc[i];
    for (int i = tid; i < 59 * 59; i += 256) WiL[i] = Wi[i];
    for (int i = tid; i < 64; i += 256) { bcombL[i] = (i < 59) ? (bf_[i] + bc[i]) : 0.f; biL[i] = (i < 59) ? bi[i] : 0.f; }
    __syncthreads();

    const int b = blockIdx.x;
    const int lane = tid & 63, wv = tid >> 6;
    const int j = lane;
    const int jj = (j < 59) ? j : 0;
    const bool act = (j < 59);

    for (int t = wv; t < 128; t += 4) {
        size_t row = (size_t)b * 128 + t;
        float v  = act ? values[row * 59 + j] : 0.f;
        float m  = act ? masks [row * 59 + j] : 0.f;
        float xv = act ? x_v   [row * 59 + j] : 0.f;
        float a1 = bcombL[jj];
        for (int k = 0; k < 59; ++k) {
            float vk = __shfl(v, k);
            a1 += vk * WfL[jj * 59 + k];
        }
        for (int k = 0; k < 59; ++k) {
            float xk = __shfl(xv, k);
            float mk = __shfl(m, k);
            a1 += xk * WcL[jj * 118 + k] + mk * WcL[jj * 118 + 59 + k];
        }
        float combo = act ? a1 : 0.f;
        float imp = biL[jj];
        for (int k = 0; k < 59; ++k) {
            float ck = __shfl(combo, k);
            imp += ck * WiL[jj * 59 + k];
        }
        if (act) out[row * 59 + j] = m * v + (1.f - m) * imp;
        float dn = fabsf(v - imp) * m;   // j>=59: m=0 -> contributes 0
        float dd = m;
        #pragma unroll
        for (int o = 32; o > 0; o >>= 1) { dn += __shfl_xor(dn, o); dd += __shfl_xor(dd, o); }
        if (lane == 0) { pnum[row] = dn; pden[row] = dd; }
    }
}

// ---------------------------------------------------------------------------
// loss reduction: sum_t ( sum_b num / (sum_b den + 1e-5) )
// ---------------------------------------------------------------------------
__global__ void loss_kernel(const float* __restrict__ pnum, const float* __restrict__ pden,
                            float* __restrict__ out)
{
    __shared__ float red[128];
    int t = threadIdx.x;   // 0..127
    float sn = 0.f, sd = 0.f;
    for (int b = 0; b < 512; ++b) {
        sn += pnum[(size_t)b * 128 + t];
        sd += pden[(size_t)b * 128 + t];
    }
    red[t] = sn / (sd + 1e-5f);
    __syncthreads();
    if (t == 0) {
        float s = 0.f;
        for (int i = 0; i < 128; ++i) s += red[i];
        out[3866624] = s;   // B*T*V = 512*128*59
    }
}

// ---------------------------------------------------------------------------
extern "C" void kernel_launch(void* const* d_in, const int* in_sizes, int n_in,
                              void* d_out, int out_size, void* d_ws, size_t ws_size,
                              hipStream_t stream)
{
    const float* values   = (const float*)d_in[0];
    const float* masks    = (const float*)d_in[1];
    const float* deltas_f = (const float*)d_in[2];
    const float* deltas_b = (const float*)d_in[3];
    const float* Wih = (const float*)d_in[4];
    const float* Whh = (const float*)d_in[5];
    const float* bih = (const float*)d_in[6];
    const float* bhh = (const float*)d_in[7];
    const float* Wh  = (const float*)d_in[8];
    const float* bh  = (const float*)d_in[9];
    const float* Wf  = (const float*)d_in[10];
    const float* bf_ = (const float*)d_in[11];
    const float* Wc  = (const float*)d_in[12];
    const float* bc  = (const float*)d_in[13];
    const float* Wi  = (const float*)d_in[14];
    const float* bi  = (const float*)d_in[15];
    float* out = (float*)d_out;

    // workspace carve (~205 MB total)
    uint8_t* ws = (uint8_t*)d_ws;
    size_t off = 0;
    auto alloc = [&](size_t bytes) -> void* {
        void* p = ws + off;
        off = (off + bytes + 255) & ~((size_t)255);
        return p;
    };
    ushort_t* xcat_f = (ushort_t*)alloc(128ULL * 512 * 192 * 2);
    ushort_t* xcat_b = (ushort_t*)alloc(128ULL * 512 * 192 * 2);
    ushort_t* WhhB   = (ushort_t*)alloc(1536ULL * 512 * 2);
    ushort_t* WihB   = (ushort_t*)alloc(1536ULL * 192 * 2);
    ushort_t* WhpB   = (ushort_t*)alloc(64ULL * 1024 * 2);
    ushort_t* hfS    = (ushort_t*)alloc(128ULL * 512 * 512 * 2);
    ushort_t* hbS    = (ushort_t*)alloc(128ULL * 512 * 512 * 2);
    float*    hstate = (float*)alloc(1024ULL * 512 * 4);
    float*    x_v    = (float*)alloc(65536ULL * 59 * 4);
    float*    pnum   = (float*)alloc(65536ULL * 4);
    float*    pden   = (float*)alloc(65536ULL * 4);

    prep_kernel<<<2048, 256, 0, stream>>>(values, masks, deltas_f, deltas_b, Wih, Whh, Wh,
                                          xcat_f, xcat_b, WhhB, WihB, WhpB,
                                          hfS, hbS, hstate);

    // 127 GRU steps (step t consumes history slot t, produces slot t+1).
    // Slot 127 is the last one consumed by x_v; step 127's update is unused.
    for (int t = 0; t < 127; ++t) {
        step_kernel<<<dim3(16, 16), 512, 0, stream>>>(
            hfS + (size_t)t * 512 * 512, hbS + (size_t)t * 512 * 512,
            hfS + (size_t)(t + 1) * 512 * 512, hbS + (size_t)(t + 1) * 512 * 512,
            xcat_f + (size_t)t * 512 * 192, xcat_b + (size_t)t * 512 * 192,
            WhhB, WihB, bih, bhh, hstate);
    }

    xv_kernel<<<512, 256, 0, stream>>>(hfS, hbS, WhpB, bh, x_v);
    post_kernel<<<512, 256, 0, stream>>>(values, masks, x_v, Wf, bf_, Wc, bc, Wi, bi,
                                         out, pnum, pden);
    loss_kernel<<<1, 128, 0, stream>>>(pnum, pden, out);
}